// Round 1
// baseline (431.495 us; speedup 1.0000x reference)
//
#include <hip/hip_runtime.h>
#include <math.h>

#define H 1024
#define V 50257
#define L 512
#define OUTB 2048          // blocks for fused output matvec
#define OUTW (OUTB * 4)    // total waves in k_out = 8192

__device__ __forceinline__ float wave_sum(float v) {
#pragma unroll
    for (int off = 32; off; off >>= 1) v += __shfl_xor(v, off, 64);
    return v;
}
__device__ __forceinline__ float wave_max(float v) {
#pragma unroll
    for (int off = 32; off; off >>= 1) v = fmaxf(v, __shfl_xor(v, off, 64));
    return v;
}
__device__ __forceinline__ float sigmoidf(float x) { return 1.f / (1.f + expf(-x)); }

// ---- K1: attn_logits[l] = dot(cat(emb, h0), W_attn[l]) + b_attn[l]
//          (+ zero ws_aa for K2's atomics; runs strictly before K2 in-stream)
__global__ void k_attn_logits(const int* __restrict__ inp, const float* __restrict__ h0,
                              const float* __restrict__ emb_table,
                              const float* __restrict__ W_attn, const float* __restrict__ b_attn,
                              float* __restrict__ logits, float* __restrict__ ws_aa) {
    if (blockIdx.x < 4) ws_aa[blockIdx.x * 256 + threadIdx.x] = 0.f;
    int wave = (blockIdx.x * blockDim.x + threadIdx.x) >> 6;
    int lane = threadIdx.x & 63;
    if (wave >= L) return;
    const float* emb = emb_table + (size_t)inp[0] * H;
    const float* wrow = W_attn + (size_t)wave * (2 * H);
    float acc = 0.f;
#pragma unroll
    for (int it = 0; it < 8; ++it) {
        int k = it * 256 + lane * 4;
        float4 wv = *(const float4*)(wrow + k);
        const float* src = (k < H) ? (emb + k) : (h0 + (k - H));
        float4 xv = *(const float4*)src;
        acc += wv.x * xv.x + wv.y * xv.y + wv.z * xv.z + wv.w * xv.w;
    }
    acc = wave_sum(acc);
    if (lane == 0) logits[wave] = acc + b_attn[wave];
}

// ---- K2 (fused softmax + attn_applied): each of 64 blocks redundantly reduces
//      the 512 logits (L2-hot), then accumulates its 8 encoder rows via atomics.
//      Block 0 also writes the attn_weights output.
__global__ void k_softmax_attn(const float* __restrict__ logits, const float* __restrict__ enc,
                               float* __restrict__ out_attn, float* __restrict__ ws_aa) {
    __shared__ float sh[4];
    __shared__ float shm, shs;
    int t = threadIdx.x, lane = t & 63, wid = t >> 6;
    float v0 = logits[t], v1 = logits[t + 256];
    float m = wave_max(fmaxf(v0, v1));
    if (lane == 0) sh[wid] = m;
    __syncthreads();
    if (t == 0) shm = fmaxf(fmaxf(sh[0], sh[1]), fmaxf(sh[2], sh[3]));
    __syncthreads();
    m = shm;
    float e0 = expf(v0 - m), e1 = expf(v1 - m);
    float s = wave_sum(e0 + e1);
    if (lane == 0) sh[wid] = s;
    __syncthreads();
    if (t == 0) shs = sh[0] + sh[1] + sh[2] + sh[3];
    __syncthreads();
    float inv = 1.f / shs;
    if (blockIdx.x == 0) {
        out_attn[t]       = e0 * inv;
        out_attn[t + 256] = e1 * inv;
    }
    float4 acc = make_float4(0.f, 0.f, 0.f, 0.f);
#pragma unroll
    for (int r = 0; r < 8; ++r) {
        int l = blockIdx.x * 8 + r;
        float w = expf(logits[l] - m) * inv;
        float4 e = *(const float4*)(enc + (size_t)l * H + t * 4);
        acc.x += w * e.x; acc.y += w * e.y; acc.z += w * e.z; acc.w += w * e.w;
    }
    atomicAdd(&ws_aa[t * 4 + 0], acc.x);
    atomicAdd(&ws_aa[t * 4 + 1], acc.y);
    atomicAdd(&ws_aa[t * 4 + 2], acc.z);
    atomicAdd(&ws_aa[t * 4 + 3], acc.w);
}

// ---- K3: x[r] = relu(dot(cat(emb, attn_applied), W_comb[r]) + b_comb[r])
__global__ void k_comb(const int* __restrict__ inp, const float* __restrict__ emb_table,
                       const float* __restrict__ ws_aa, const float* __restrict__ W_comb,
                       const float* __restrict__ b_comb, float* __restrict__ ws_x) {
    int wave = (blockIdx.x * blockDim.x + threadIdx.x) >> 6;
    int lane = threadIdx.x & 63;
    if (wave >= H) return;
    const float* emb = emb_table + (size_t)inp[0] * H;
    const float* wrow = W_comb + (size_t)wave * (2 * H);
    float acc = 0.f;
#pragma unroll
    for (int it = 0; it < 8; ++it) {
        int k = it * 256 + lane * 4;
        float4 wv = *(const float4*)(wrow + k);
        const float* src = (k < H) ? (emb + k) : (ws_aa + (k - H));
        float4 xv = *(const float4*)src;
        acc += wv.x * xv.x + wv.y * xv.y + wv.z * xv.z + wv.w * xv.w;
    }
    acc = wave_sum(acc);
    if (lane == 0) ws_x[wave] = fmaxf(acc + b_comb[wave], 0.f);
}

// ---- K4 (fused gates + LSTM): block j -> hidden element j; wave w -> gate row w*H+j
__global__ void k_gates_lstm(const float* __restrict__ ws_x, const float* __restrict__ h0,
                             const float* __restrict__ c0,
                             const float* __restrict__ W_ih, const float* __restrict__ W_hh,
                             const float* __restrict__ b_ih, const float* __restrict__ b_hh,
                             float* __restrict__ out_h1, float* __restrict__ out_c1) {
    __shared__ float g[4];
    int j = blockIdx.x;
    int wv = threadIdx.x >> 6;   // 0..3 = i,f,g,o
    int lane = threadIdx.x & 63;
    int row = wv * H + j;
    const float* wi = W_ih + (size_t)row * H;
    const float* wh = W_hh + (size_t)row * H;
    float acc = 0.f;
#pragma unroll
    for (int it = 0; it < 4; ++it) {
        int k = it * 256 + lane * 4;
        float4 a = *(const float4*)(wi + k);
        float4 xv = *(const float4*)(ws_x + k);
        acc += a.x * xv.x + a.y * xv.y + a.z * xv.z + a.w * xv.w;
        float4 b = *(const float4*)(wh + k);
        float4 hv = *(const float4*)(h0 + k);
        acc += b.x * hv.x + b.y * hv.y + b.z * hv.z + b.w * hv.w;
    }
    acc = wave_sum(acc);
    if (lane == 0) g[wv] = acc + b_ih[row] + b_hh[row];
    __syncthreads();
    if (threadIdx.x == 0) {
        float ig = sigmoidf(g[0]);
        float fg = sigmoidf(g[1]);
        float gg = tanhf(g[2]);
        float og = sigmoidf(g[3]);
        float c1 = fg * c0[j] + ig * gg;
        out_c1[j] = c1;
        out_h1[j] = og * tanhf(c1);
    }
}

// ---- K5: logits[v] = dot(h1, W_out[v]) + b_out[v]  (206 MB stream), plus a
//      per-block online (max, sumexp) partial for the log-softmax.
__global__ void k_out(const float* __restrict__ h1, const float* __restrict__ W_out,
                      const float* __restrict__ b_out, float* __restrict__ logp,
                      float* __restrict__ pair) {
    __shared__ float shm[4], shs[4];
    int lane = threadIdx.x & 63, wv = threadIdx.x >> 6;
    int w = blockIdx.x * 4 + wv;
    float4 hv[4];
#pragma unroll
    for (int it = 0; it < 4; ++it) hv[it] = *(const float4*)(h1 + it * 256 + lane * 4);
    float m = -INFINITY, s = 0.f;
    for (int row = w; row < V; row += OUTW) {
        const float* wrow = W_out + (size_t)row * H;
        float acc = 0.f;
#pragma unroll
        for (int it = 0; it < 4; ++it) {
            float4 a = *(const float4*)(wrow + it * 256 + lane * 4);
            acc += a.x * hv[it].x + a.y * hv[it].y + a.z * hv[it].z + a.w * hv[it].w;
        }
        acc = wave_sum(acc) + b_out[row];
        if (lane == 0) logp[row] = acc;
        float nm = fmaxf(m, acc);
        s = s * expf(m - nm) + expf(acc - nm);
        m = nm;
    }
    if (lane == 0) { shm[wv] = m; shs[wv] = s; }
    __syncthreads();
    if (threadIdx.x == 0) {
        float M = shm[0], S = shs[0];
#pragma unroll
        for (int i = 1; i < 4; ++i) {
            float nm = fmaxf(M, shm[i]);
            S = S * expf(M - nm) + shs[i] * expf(shm[i] - nm);
            M = nm;
        }
        pair[blockIdx.x * 2]     = M;
        pair[blockIdx.x * 2 + 1] = S;
    }
}

// ---- K6: merge the 2048 (max,sumexp) pairs in-block, subtract LSE grid-wide
__global__ void k_sub(float* __restrict__ logp, const float* __restrict__ pair) {
    __shared__ float shm[4], shs[4];
    int t = threadIdx.x, lane = t & 63, wv = t >> 6;
    float m = -INFINITY, s = 0.f;
#pragma unroll
    for (int i = 0; i < 8; ++i) {
        int p = i * 256 + t;       // 8*256 = 2048 pairs
        float pm = pair[p * 2], ps = pair[p * 2 + 1];
        float nm = fmaxf(m, pm);
        s = s * expf(m - nm) + ps * expf(pm - nm);
        m = nm;
    }
#pragma unroll
    for (int off = 32; off; off >>= 1) {
        float om = __shfl_xor(m, off, 64), os = __shfl_xor(s, off, 64);
        float nm = fmaxf(m, om);
        s = s * expf(m - nm) + os * expf(om - nm);
        m = nm;
    }
    if (lane == 0) { shm[wv] = m; shs[wv] = s; }
    __syncthreads();
    float M = shm[0], S = shs[0];
#pragma unroll
    for (int i = 1; i < 4; ++i) {
        float nm = fmaxf(M, shm[i]);
        S = S * expf(M - nm) + shs[i] * expf(shm[i] - nm);
        M = nm;
    }
    float lse = M + logf(S);
    int v = blockIdx.x * 256 + t;
    if (v < V) logp[v] -= lse;
}

extern "C" void kernel_launch(void* const* d_in, const int* in_sizes, int n_in,
                              void* d_out, int out_size, void* d_ws, size_t ws_size,
                              hipStream_t stream) {
    const int*   inp     = (const int*)d_in[0];
    const float* h0      = (const float*)d_in[1];
    const float* c0      = (const float*)d_in[2];
    const float* enc     = (const float*)d_in[3];
    const float* emb     = (const float*)d_in[4];
    const float* W_attn  = (const float*)d_in[5];
    const float* b_attn  = (const float*)d_in[6];
    const float* W_comb  = (const float*)d_in[7];
    const float* b_comb  = (const float*)d_in[8];
    const float* W_ih    = (const float*)d_in[9];
    const float* W_hh    = (const float*)d_in[10];
    const float* b_ih    = (const float*)d_in[11];
    const float* b_hh    = (const float*)d_in[12];
    const float* W_out   = (const float*)d_in[13];
    const float* b_out   = (const float*)d_in[14];

    float* out      = (float*)d_out;
    float* out_logp = out;                  // V
    float* out_h1   = out + V;              // H
    float* out_c1   = out + V + H;          // H
    float* out_attn = out + V + 2 * H;      // L

    float* ws        = (float*)d_ws;
    float* ws_logits = ws;                  // L
    float* ws_aa     = ws + 512;            // H
    float* ws_x      = ws + 512 + 1024;     // H
    float* ws_pair   = ws + 512 + 2048;     // 2*OUTB

    k_attn_logits<<<128, 256, 0, stream>>>(inp, h0, emb, W_attn, b_attn, ws_logits, ws_aa);
    k_softmax_attn<<<64, 256, 0, stream>>>(ws_logits, enc, out_attn, ws_aa);
    k_comb<<<256, 256, 0, stream>>>(inp, emb, ws_aa, W_comb, b_comb, ws_x);
    k_gates_lstm<<<1024, 256, 0, stream>>>(ws_x, h0, c0, W_ih, W_hh, b_ih, b_hh, out_h1, out_c1);
    k_out<<<OUTB, 256, 0, stream>>>(out_h1, W_out, b_out, out_logp, ws_pair);
    k_sub<<<(V + 255) / 256, 256, 0, stream>>>(out_logp, ws_pair);
}